// Round 16
// baseline (1665.227 us; speedup 1.0000x reference)
//
#include <hip/hip_runtime.h>
#include <hip/hip_fp16.h>
#include <hip/hip_bf16.h>

#define B_ 16
#define N_ 64
#define T_ 32
#define D_ 512
#define H_ 256
#define K_ 13
#define S_ 2048
#define G4_ 1024

typedef float f32x4 __attribute__((ext_vector_type(4)));
typedef short s16x8 __attribute__((ext_vector_type(8)));
typedef int   i32x4 __attribute__((ext_vector_type(4)));
typedef _Float16 f16x8 __attribute__((ext_vector_type(8)));

#define LOG2E 1.44269504f
#define INVQ  2.0505324e-5f    /* 1/(384*127) */
#define INVQ2 2.9582873e-5f    /* INVQ * log2e */

// barrier with LDS-only drain: do NOT wait vmcnt (global loads/stores stay in flight)
#define BAR() do { \
  asm volatile("s_waitcnt lgkmcnt(0)" ::: "memory"); \
  __builtin_amdgcn_s_barrier(); \
  __builtin_amdgcn_sched_barrier(0); \
} while (0)

// log2e-unit gates: y = x*log2e; v_exp_f32 is natively 2^x, v_rcp via builtin (fast, 1ulp)
__device__ __forceinline__ float sigm2(float y){ return __builtin_amdgcn_rcpf(1.0f + exp2f(-y)); }
__device__ __forceinline__ float tanh2(float y){ return 1.0f - 2.0f*__builtin_amdgcn_rcpf(1.0f + exp2f(2.0f*y)); }

// ---------- prefix sums over segment lengths + mw -> f16 [16][512] (rows 13-15 zero) ----------
__global__ void k_prep(const int* __restrict__ length, int* __restrict__ cum, int* __restrict__ doc,
                       const float* __restrict__ mw, __half* __restrict__ mwh){
  const int b = threadIdx.x >> 6, n = threadIdx.x & 63;
  const int v = length[b*N_ + n];
  int x = v;
  #pragma unroll
  for (int d = 1; d < 64; d <<= 1){
    int y = __shfl_up(x, d);
    if (n >= d) x += y;
  }
  cum[b*N_ + n] = x - v;          // exclusive
  if (n == 63) doc[b] = x;        // doc_len
  // mw cast: 16*512 = 8192 halves, 8 per thread
  #pragma unroll
  for (int k = 0; k < 8; ++k){
    const int i = threadIdx.x + k*1024;
    mwh[i] = (i < 13*512) ? __float2half(mw[i]) : __float2half(0.0f);
  }
}

// ---------- cast weights: w_ih -> bf16 [2048][512]; w_hh -> i8 [dir][1024][256] ----------
__global__ __launch_bounds__(256) void k_cast(const float* __restrict__ wf, const float* __restrict__ wb,
                       const float* __restrict__ hf, const float* __restrict__ hb,
                       ushort* __restrict__ wih, signed char* __restrict__ whh8){
  const int i = blockIdx.x*256 + threadIdx.x;
  if (i < 2*G4_*D_){
    const int dir = i / (G4_*D_); const int r = i % (G4_*D_);
    const float v = dir ? wb[r] : wf[r];
    ((__hip_bfloat16*)wih)[i] = __float2bfloat16(v);
  } else {
    const int j2 = i - 2*G4_*D_;
    if (j2 < 2*G4_*H_){
      const int dir = j2 >> 18; const int r = j2 & 262143;
      const float v = (dir ? hb : hf)[r];
      int q = (int)rintf(v * 384.0f);
      whh8[j2] = (signed char)min(127, max(-127, q));
    }
  }
}

// ---------- scatter source map + packed tags ----------
__global__ __launch_bounds__(256) void k_srcmap(const int* __restrict__ length, const int* __restrict__ cum,
                         const int* __restrict__ tags, int* __restrict__ src, int* __restrict__ ntag){
  const int i = blockIdx.x*256 + threadIdx.x;            // B*N*T = 32768
  const int b = i >> 11, nt = i & 2047, n = nt >> 5, t = nt & 31;
  if (t < length[b*N_ + n]){
    const int dest = cum[b*N_ + n] + t;
    src[b*S_ + dest] = nt;
    ntag[b*S_ + dest] = tags[i];
  }
}

// ---------- build packed new_x (bf16) + mask output ----------
__global__ __launch_bounds__(256) void k_newx(const float* __restrict__ x, const float* __restrict__ gcn,
                      const int* __restrict__ src, const int* __restrict__ doc,
                      ushort* __restrict__ nx, float* __restrict__ mask_out){
  const int r = blockIdx.x; const int b = r >> 11, s = r & 2047;
  const int L = doc[b];
  const int d = threadIdx.x*2;
  const float2 g2 = *(const float2*)&gcn[((size_t)(b*N_ + (s>>5)))*D_ + d];
  float v0 = g2.x, v1 = g2.y;
  if (s < L){
    const int nt = src[r];
    const float2 x2 = *(const float2*)&x[((size_t)(b*S_ + nt))*D_ + d];
    v0 += x2.x; v1 += x2.y;
  }
  __hip_bfloat16* o = (__hip_bfloat16*)nx + (size_t)r*D_ + d;
  o[0] = __float2bfloat16(v0); o[1] = __float2bfloat16(v1);
  if (threadIdx.x == 0) mask_out[r] = (s < L) ? 1.0f : 0.0f;
}

// ---------- input projection GEMM (r12 form) ----------
// pre layout: pre[b][s][dir*1024 + u*4 + g]  (f16, bias added, *log2e)
__global__ __launch_bounds__(256) void k_gemm(const ushort* __restrict__ A, const ushort* __restrict__ Bw,
    const float* __restrict__ bias_f, const float* __restrict__ bias_b,
    const int* __restrict__ doc, __half* __restrict__ pre){
  const int m0 = blockIdx.x*128, n0 = blockIdx.y*128;
  const int b = m0 >> 11, s0 = m0 & 2047;
  if (s0 >= doc[b]) return;
  __shared__ __align__(16) ushort la[128*40];
  __shared__ __align__(16) ushort lb[128*40];
  const int tid = threadIdx.x, lane = tid & 63, w = tid >> 6;
  const int wr = w >> 1, wc = w & 1;
  const int fr = lane & 15, fq = lane >> 4;
  f32x4 acc[4][4] = {};
  const int srow = tid >> 1;
  const int sko  = (tid & 1)*16;
  for (int kt = 0; kt < 16; ++kt){
    const int k0 = kt*32;
    const float4 a0 = *(const float4*)&A[(size_t)(m0+srow)*512 + k0 + sko];
    const float4 a1 = *(const float4*)&A[(size_t)(m0+srow)*512 + k0 + sko + 8];
    const float4 b0 = *(const float4*)&Bw[(size_t)(n0+srow)*512 + k0 + sko];
    const float4 b1 = *(const float4*)&Bw[(size_t)(n0+srow)*512 + k0 + sko + 8];
    *(float4*)&la[srow*40 + sko]     = a0;
    *(float4*)&la[srow*40 + sko + 8] = a1;
    *(float4*)&lb[srow*40 + sko]     = b0;
    *(float4*)&lb[srow*40 + sko + 8] = b1;
    __syncthreads();
    s16x8 af[4], bfr[4];
    #pragma unroll
    for (int mi=0; mi<4; ++mi) af[mi] = *(const s16x8*)&la[(wr*64+mi*16+fr)*40 + fq*8];
    #pragma unroll
    for (int ni=0; ni<4; ++ni) bfr[ni] = *(const s16x8*)&lb[(wc*64+ni*16+fr)*40 + fq*8];
    #pragma unroll
    for (int mi=0; mi<4; ++mi){
      #pragma unroll
      for (int ni=0; ni<4; ++ni){
        acc[mi][ni] = __builtin_amdgcn_mfma_f32_16x16x32_bf16(af[mi], bfr[ni], acc[mi][ni], 0, 0, 0);
      }
    }
    __syncthreads();
  }
  #pragma unroll
  for (int ni=0; ni<4; ++ni){
    const int n = n0 + wc*64 + ni*16 + fr;         // gate-row index: dir*1024 + g*256 + u
    const float bv = (n < 1024) ? bias_f[n] : bias_b[n-1024];
    const int dir = n >> 10, g = (n >> 8) & 3, u = n & 255;
    const int col = dir*1024 + u*4 + g;            // remapped column
    #pragma unroll
    for (int mi=0; mi<4; ++mi){
      const int mb = m0 + wr*64 + mi*16 + fq*4;
      #pragma unroll
      for (int j=0; j<4; ++j)
        pre[(size_t)(mb+j)*2048 + col] = __float2half((acc[mi][ni][j] + bv)*LOG2E);
    }
  }
}

// ---------- recurrent LSTM: EXACT r12 structure (proven 948us) ----------
__global__ __launch_bounds__(512, 2) void k_recur16(
    const signed char* __restrict__ W8,
    const __half* __restrict__ pre, const int* __restrict__ doc,
    __half* __restrict__ outh)
{
  const int b = blockIdx.x >> 1, dir = blockIdx.x & 1;
  const int tid = threadIdx.x, lane = tid & 63, wv = tid >> 6;
  const int L = doc[b];

  __shared__ __align__(16) signed char hq[2][256];   // i8 h, double-buffered

  if (tid < 128) ((unsigned*)hq)[tid] = 0u;          // h_{-1} = 0

  // W_hh i8 B-fragments: lane holds W[row=g*256+wv*32+nt*16+(lane&15)][kt*64+(lane>>4)*16 ..+16]
  i32x4 wfrag[2][4][4];
  #pragma unroll
  for (int nt = 0; nt < 2; ++nt)
    #pragma unroll
    for (int g = 0; g < 4; ++g){
      const int row = g*256 + wv*32 + nt*16 + (lane & 15);
      #pragma unroll
      for (int kt = 0; kt < 4; ++kt)
        wfrag[nt][g][kt] = *(const i32x4*)&W8[(size_t)dir*262144 + (size_t)row*256 + kt*64 + (lane>>4)*16];
    }

  const int u = wv*32 + (lane & 31);     // unit owned in gate phase (lanes 32-63 mirror 0-31)
  const int koff = (lane >> 4)*16;       // 16-byte k-chunk this lane supplies to the A-frag
  const int pos0 = dir ? (L-1) : 0;
  const __half* pp = pre + ((size_t)(b*S_ + pos0))*2048 + dir*1024 + u*4;
  __half*       op = outh + ((size_t)(b*S_ + pos0))*512 + dir*256 + u;
  const ptrdiff_t dp  = dir ? -2048 : 2048;   // halves per step (pre row)
  const ptrdiff_t dph = dir ? -512  : 512;    // halves per step (outh row)

  float cst = 0.f;
  uint2 pv, pvn = {0,0};
  pv = *(const uint2*)pp;                // lanes 32-63 load valid duplicates of lanes 0-31
  const i32x4 z = {0,0,0,0};
  BAR();

  for (int t = 0; t < L; ++t){
    // prefetch next step's pre operands (consumed after MFMA phase -> latency hidden)
    if (t+1 < L) pvn = *(const uint2*)(pp + dp);
    pp += dp;

    const int rbuf = (t+1) & 1, wbuf = t & 1;

    // broadcast A-fragments: uniform per 16-lane group -> LDS broadcast, conflict-free
    i32x4 af[4];
    #pragma unroll
    for (int kt = 0; kt < 4; ++kt)
      af[kt] = *(const i32x4*)&hq[rbuf][kt*64 + koff];

    // chained K-accumulate for one (nt, gate); all C rows identical -> a[0] is the gate sum
    auto chain4 = [&](const i32x4* w4) -> int {
      i32x4 a = __builtin_amdgcn_mfma_i32_16x16x64_i8(af[0], w4[0], z, 0, 0, 0);
      a = __builtin_amdgcn_mfma_i32_16x16x64_i8(af[1], w4[1], a, 0, 0, 0);
      a = __builtin_amdgcn_mfma_i32_16x16x64_i8(af[2], w4[2], a, 0, 0, 0);
      a = __builtin_amdgcn_mfma_i32_16x16x64_i8(af[3], w4[3], a, 0, 0, 0);
      return a[0];
    };

    const bool hi = (lane & 16) != 0;
    const __half2* ph = (const __half2*)&pv;
    const float2 p01 = __half22float2(ph[0]);
    const float2 p23 = __half22float2(ph[1]);

    // gates i,f,g first; c-chain VALU overlaps the o-gate MFMAs below
    const int i0 = chain4(wfrag[0][0]), i1 = chain4(wfrag[1][0]);
    const int f0 = chain4(wfrag[0][1]), f1 = chain4(wfrag[1][1]);
    const int q0 = chain4(wfrag[0][2]), q1 = chain4(wfrag[1][2]);
    const float giy = (float)(hi ? i1 : i0)*INVQ2 + p01.x;
    const float gfy = (float)(hi ? f1 : f0)*INVQ2 + p01.y;
    const float ggy = (float)(hi ? q1 : q0)*INVQ2 + p23.x;
    const int o0 = chain4(wfrag[0][3]), o1 = chain4(wfrag[1][3]);
    const float c = sigm2(gfy)*cst + sigm2(giy)*tanh2(ggy);
    cst = c;
    const float goy = (float)(hi ? o1 : o0)*INVQ2 + p23.y;
    const float hval = sigm2(goy)*tanh2(c*LOG2E);

    if (lane < 32){
      *op = __float2half(hval);
      hq[wbuf][u] = (signed char)(int)rintf(hval*127.0f);  // h in (-1,1): no clamp needed
    }
    op += dph;
    pv = pvn;
    BAR();
  }
}

// ---------- logits via MFMA f16: logits[r][k] = outh[r][:] . mw[k][:] + mb[k] ----------
// outh is zeroed for dead rows (memsetAsync) -> dead rows give logits = mb automatically.
// grid = 512 blocks x 256 thr; block handles 64 rows (wave wv owns rows blk*64+wv*16 ..+16).
__global__ __launch_bounds__(256) void k_logits(const __half* __restrict__ outh, const __half* __restrict__ mwh,
    const float* __restrict__ mb, float* __restrict__ logits){
  __shared__ __align__(16) __half lw[16][520];     // mw f16, padded rows
  const int tid = threadIdx.x, lane = tid & 63, wv = tid >> 6;
  // stage mw: 8192 halves, 8 per thread (uint4 = 16 B = 8 halves, matches tid*8 stride)
  {
    const int i = tid*8;
    #pragma unroll
    for (int k = 0; k < 4; ++k){
      const int ii = i + k*2048;
      *(uint4*)&lw[ii >> 9][ii & 511] = *(const uint4*)&mwh[ii];
    }
  }
  __syncthreads();
  const int fr = lane & 15, fq = lane >> 4;
  const int row0 = blockIdx.x*64 + wv*16;
  f32x4 acc = {0.f, 0.f, 0.f, 0.f};
  #pragma unroll
  for (int kt = 0; kt < 16; ++kt){
    const f16x8 a  = *(const f16x8*)&outh[(size_t)(row0 + fr)*512 + kt*32 + fq*8];
    const f16x8 bf = *(const f16x8*)&lw[fr][kt*32 + fq*8];
    acc = __builtin_amdgcn_mfma_f32_16x16x32_f16(a, bf, acc, 0, 0, 0);
  }
  if (fr < 13){
    const float bv = mb[fr];
    #pragma unroll
    for (int j = 0; j < 4; ++j)
      logits[(size_t)(row0 + fq*4 + j)*13 + fr] = acc[j] + bv;
  }
}

// ---------- CRF: one wave per batch; exp-transition matvec, log2 domain, tree-sum ----------
__global__ void k_crf(const float* __restrict__ logits, const int* __restrict__ ntag,
    const int* __restrict__ doc, const float* __restrict__ trans,
    const float* __restrict__ stt, const float* __restrict__ ent, float* __restrict__ ll){
  const int b = blockIdx.x, lane = threadIdx.x;
  const int L = doc[b];
  const float* lg = logits + (size_t)b*S_*13;
  float et2[13];
  #pragma unroll
  for (int i=0; i<13; ++i) et2[i] = (lane < 13) ? exp2f(trans[i*13 + lane]*LOG2E) : 0.f;
  float al = (lane < 13) ? (stt[lane] + lg[lane])*LOG2E : -1e30f;
  float e_nxt = (L > 1 && lane < 13) ? lg[13 + lane]*LOG2E : 0.f;
  for (int t=1; t<L; ++t){
    const float e = e_nxt;
    if (t+1 < L && lane < 13) e_nxt = lg[(size_t)(t+1)*13 + lane]*LOG2E;
    float m = al;
    #pragma unroll
    for (int off = 1; off < 16; off <<= 1) m = fmaxf(m, __shfl_xor(m, off));
    const float a = exp2f(al - m);
    float tv[13];
    #pragma unroll
    for (int i=0; i<13; ++i) tv[i] = __shfl(a, i) * et2[i];
    const float s = (((tv[0]+tv[1])+(tv[2]+tv[3])) + ((tv[4]+tv[5])+(tv[6]+tv[7])))
                  + (((tv[8]+tv[9])+(tv[10]+tv[11])) + tv[12]);
    al = m + log2f(s) + e;
  }
  float av = (lane < 13) ? al + ent[lane]*LOG2E : -1e30f;
  float m2 = -1e30f;
  #pragma unroll
  for (int i=0; i<13; ++i) m2 = fmaxf(m2, __shfl(av, i));
  float s2 = 0.f;
  #pragma unroll
  for (int i=0; i<13; ++i) s2 += exp2f(__shfl(av, i) - m2);
  const float logz = (m2 + log2f(s2)) * (1.0f/LOG2E);
  const int* tg = ntag + (size_t)b*S_;
  float num = 0.f;
  for (int t = lane; t < L; t += 64){
    const int cur = tg[t];
    num += lg[(size_t)t*13 + cur];
    if (t >= 1) num += trans[tg[t-1]*13 + cur];
  }
  #pragma unroll
  for (int off=32; off; off>>=1) num += __shfl_down(num, off);
  if (lane == 0){
    num += stt[tg[0]] + ent[tg[L-1]];
    ll[b] = num - logz;
  }
}

extern "C" void kernel_launch(void* const* d_in, const int* in_sizes, int n_in,
                              void* d_out, int out_size, void* d_ws, size_t ws_size,
                              hipStream_t stream){
  const float* x    = (const float*)d_in[0];
  const float* gcn  = (const float*)d_in[1];
  const int* length = (const int*)d_in[3];
  const int* tags   = (const int*)d_in[4];
  const float* wihf = (const float*)d_in[5];
  const float* whhf = (const float*)d_in[6];
  const float* bf   = (const float*)d_in[7];
  const float* wihb = (const float*)d_in[8];
  const float* whhb = (const float*)d_in[9];
  const float* bb   = (const float*)d_in[10];
  const float* mw   = (const float*)d_in[11];
  const float* mb   = (const float*)d_in[12];
  const float* trans= (const float*)d_in[13];
  const float* stt  = (const float*)d_in[14];
  const float* ent  = (const float*)d_in[15];

  char* ws = (char*)d_ws;
  ushort* nx   = (ushort*)(ws + 0);              // 33,554,432 B  new_x bf16
  __half* pre  = (__half*)(ws + 33554432);       // 134,217,728 B pre-activations f16 (remapped, log2e-scaled)
  __half* outh = (__half*)(ws + 167772160);      // 33,554,432 B  concat h states (f16, zeroed)
  ushort* wih  = (ushort*)(ws + 234881024);      // 2,097,152 B   w_ih bf16 [2048][512]
  signed char* whh8 = (signed char*)(ws + 236978176); // 524,288 B w_hh i8 [2][1024][256]
  __half* mwh  = (__half*)(ws + 237502464);      // 16,384 B      mw f16 [16][512] (in old slack)
  int*    src  = (int*)(ws + 238026752);         // 131,072 B
  int*    ntag = (int*)(ws + 238157824);         // 131,072 B
  int*    cum  = (int*)(ws + 238288896);         // 4,096 B
  int*    doc  = (int*)(ws + 238292992);         // 64 B

  float* logits  = (float*)d_out;                // 425,984 floats
  float* maskout = logits + 425984;              // 32,768 floats
  float* ll      = maskout + 32768;              // 16 floats

  hipLaunchKernelGGL(k_prep,   dim3(1),        dim3(1024), 0, stream, length, cum, doc, mw, mwh);
  hipLaunchKernelGGL(k_cast,   dim3(6144),     dim3(256),  0, stream, wihf, wihb, whhf, whhb, wih, whh8);
  hipLaunchKernelGGL(k_srcmap, dim3(128),      dim3(256),  0, stream, length, cum, tags, src, ntag);
  hipLaunchKernelGGL(k_newx,   dim3(32768),    dim3(256),  0, stream, x, gcn, src, doc, nx, maskout);
  hipMemsetAsync(outh, 0, 33554432, stream);     // dead rows -> h=0 -> logits=mb (matches reference)
  hipLaunchKernelGGL(k_gemm,   dim3(256, 16),  dim3(256),  0, stream, nx, wih, bf, bb, doc, pre);
  hipLaunchKernelGGL(k_recur16, dim3(32),      dim3(512),  0, stream, whh8, pre, doc, outh);
  hipLaunchKernelGGL(k_logits, dim3(512),      dim3(256),  0, stream, outh, mwh, mb, logits);
  hipLaunchKernelGGL(k_crf,    dim3(16),       dim3(64),   0, stream, logits, ntag, doc, trans, stt, ent, ll);
}

// Round 17
// 1535.367 us; speedup vs baseline: 1.0846x; 1.0846x over previous
//
#include <hip/hip_runtime.h>
#include <hip/hip_fp16.h>
#include <hip/hip_bf16.h>

#define B_ 16
#define N_ 64
#define T_ 32
#define D_ 512
#define H_ 256
#define K_ 13
#define S_ 2048
#define G4_ 1024

typedef float f32x4 __attribute__((ext_vector_type(4)));
typedef short s16x8 __attribute__((ext_vector_type(8)));
typedef int   i32x4 __attribute__((ext_vector_type(4)));

#define LOG2E 1.44269504f
#define INVQ  2.0505324e-5f    /* 1/(384*127) */
#define INVQ2 2.9582873e-5f    /* INVQ * log2e */

// barrier with LDS-only drain: do NOT wait vmcnt (global loads/stores stay in flight)
#define BAR() do { \
  asm volatile("s_waitcnt lgkmcnt(0)" ::: "memory"); \
  __builtin_amdgcn_s_barrier(); \
  __builtin_amdgcn_sched_barrier(0); \
} while (0)

// log2e-unit gates: y = x*log2e; v_exp_f32 is natively 2^x, v_rcp via builtin (fast, 1ulp)
__device__ __forceinline__ float sigm2(float y){ return __builtin_amdgcn_rcpf(1.0f + exp2f(-y)); }
__device__ __forceinline__ float tanh2(float y){ return 1.0f - 2.0f*__builtin_amdgcn_rcpf(1.0f + exp2f(2.0f*y)); }

// ---------- prefix sums over segment lengths ----------
__global__ void k_prep(const int* __restrict__ length, int* __restrict__ cum, int* __restrict__ doc){
  const int b = threadIdx.x >> 6, n = threadIdx.x & 63;
  const int v = length[b*N_ + n];
  int x = v;
  #pragma unroll
  for (int d = 1; d < 64; d <<= 1){
    int y = __shfl_up(x, d);
    if (n >= d) x += y;
  }
  cum[b*N_ + n] = x - v;          // exclusive
  if (n == 63) doc[b] = x;        // doc_len
}

// ---------- cast weights: w_ih -> bf16 [2048][512]; w_hh -> i8 [dir][1024][256] ----------
__global__ __launch_bounds__(256) void k_cast(const float* __restrict__ wf, const float* __restrict__ wb,
                       const float* __restrict__ hf, const float* __restrict__ hb,
                       ushort* __restrict__ wih, signed char* __restrict__ whh8){
  const int i = blockIdx.x*256 + threadIdx.x;
  if (i < 2*G4_*D_){
    const int dir = i / (G4_*D_); const int r = i % (G4_*D_);
    const float v = dir ? wb[r] : wf[r];
    ((__hip_bfloat16*)wih)[i] = __float2bfloat16(v);
  } else {
    const int j2 = i - 2*G4_*D_;
    if (j2 < 2*G4_*H_){
      const int dir = j2 >> 18; const int r = j2 & 262143;
      const float v = (dir ? hb : hf)[r];
      int q = (int)rintf(v * 384.0f);
      whh8[j2] = (signed char)min(127, max(-127, q));
    }
  }
}

// ---------- scatter source map + packed tags ----------
__global__ __launch_bounds__(256) void k_srcmap(const int* __restrict__ length, const int* __restrict__ cum,
                         const int* __restrict__ tags, int* __restrict__ src, int* __restrict__ ntag){
  const int i = blockIdx.x*256 + threadIdx.x;            // B*N*T = 32768
  const int b = i >> 11, nt = i & 2047, n = nt >> 5, t = nt & 31;
  if (t < length[b*N_ + n]){
    const int dest = cum[b*N_ + n] + t;
    src[b*S_ + dest] = nt;
    ntag[b*S_ + dest] = tags[i];
  }
}

// ---------- build packed new_x (bf16) + mask output ----------
__global__ __launch_bounds__(256) void k_newx(const float* __restrict__ x, const float* __restrict__ gcn,
                      const int* __restrict__ src, const int* __restrict__ doc,
                      ushort* __restrict__ nx, float* __restrict__ mask_out){
  const int r = blockIdx.x; const int b = r >> 11, s = r & 2047;
  const int L = doc[b];
  const int d = threadIdx.x*2;
  const float2 g2 = *(const float2*)&gcn[((size_t)(b*N_ + (s>>5)))*D_ + d];
  float v0 = g2.x, v1 = g2.y;
  if (s < L){
    const int nt = src[r];
    const float2 x2 = *(const float2*)&x[((size_t)(b*S_ + nt))*D_ + d];
    v0 += x2.x; v1 += x2.y;
  }
  __hip_bfloat16* o = (__hip_bfloat16*)nx + (size_t)r*D_ + d;
  o[0] = __float2bfloat16(v0); o[1] = __float2bfloat16(v1);
  if (threadIdx.x == 0) mask_out[r] = (s < L) ? 1.0f : 0.0f;
}

// ---------- input projection GEMM ----------
// pre layout: pre[b][s][dir*1024 + u*4 + g]  (f16, bias added, *log2e)
__global__ __launch_bounds__(256) void k_gemm(const ushort* __restrict__ A, const ushort* __restrict__ Bw,
    const float* __restrict__ bias_f, const float* __restrict__ bias_b,
    const int* __restrict__ doc, __half* __restrict__ pre){
  const int m0 = blockIdx.x*128, n0 = blockIdx.y*128;
  const int b = m0 >> 11, s0 = m0 & 2047;
  if (s0 >= doc[b]) return;
  __shared__ __align__(16) ushort la[128*40];
  __shared__ __align__(16) ushort lb[128*40];
  const int tid = threadIdx.x, lane = tid & 63, w = tid >> 6;
  const int wr = w >> 1, wc = w & 1;
  const int fr = lane & 15, fq = lane >> 4;
  f32x4 acc[4][4] = {};
  const int srow = tid >> 1;
  const int sko  = (tid & 1)*16;
  for (int kt = 0; kt < 16; ++kt){
    const int k0 = kt*32;
    const float4 a0 = *(const float4*)&A[(size_t)(m0+srow)*512 + k0 + sko];
    const float4 a1 = *(const float4*)&A[(size_t)(m0+srow)*512 + k0 + sko + 8];
    const float4 b0 = *(const float4*)&Bw[(size_t)(n0+srow)*512 + k0 + sko];
    const float4 b1 = *(const float4*)&Bw[(size_t)(n0+srow)*512 + k0 + sko + 8];
    *(float4*)&la[srow*40 + sko]     = a0;
    *(float4*)&la[srow*40 + sko + 8] = a1;
    *(float4*)&lb[srow*40 + sko]     = b0;
    *(float4*)&lb[srow*40 + sko + 8] = b1;
    __syncthreads();
    s16x8 af[4], bfr[4];
    #pragma unroll
    for (int mi=0; mi<4; ++mi) af[mi] = *(const s16x8*)&la[(wr*64+mi*16+fr)*40 + fq*8];
    #pragma unroll
    for (int ni=0; ni<4; ++ni) bfr[ni] = *(const s16x8*)&lb[(wc*64+ni*16+fr)*40 + fq*8];
    #pragma unroll
    for (int mi=0; mi<4; ++mi){
      #pragma unroll
      for (int ni=0; ni<4; ++ni){
        acc[mi][ni] = __builtin_amdgcn_mfma_f32_16x16x32_bf16(af[mi], bfr[ni], acc[mi][ni], 0, 0, 0);
      }
    }
    __syncthreads();
  }
  #pragma unroll
  for (int ni=0; ni<4; ++ni){
    const int n = n0 + wc*64 + ni*16 + fr;         // gate-row index: dir*1024 + g*256 + u
    const float bv = (n < 1024) ? bias_f[n] : bias_b[n-1024];
    const int dir = n >> 10, g = (n >> 8) & 3, u = n & 255;
    const int col = dir*1024 + u*4 + g;            // remapped column
    #pragma unroll
    for (int mi=0; mi<4; ++mi){
      const int mb = m0 + wr*64 + mi*16 + fq*4;
      #pragma unroll
      for (int j=0; j<4; ++j)
        pre[(size_t)(mb+j)*2048 + col] = __float2half((acc[mi][ni][j] + bv)*LOG2E);
    }
  }
}

// ---------- recurrent LSTM: one block per (batch,dir) chain; i8 W_hh in AGPRs ----------
// grid = 32: blockIdx = b*2 + dir. 512 threads / 8 waves / 2 waves per SIMD (proven envelope).
// Broadcast-A (all C rows identical); g-major chained MFMAs so the c-chain VALU runs under
// the o-gate's MFMAs; native exp2 + v_rcp gates (pre is pre-scaled by log2e in k_gemm).
__global__ __launch_bounds__(512, 2) void k_recur17(
    const signed char* __restrict__ W8,
    const __half* __restrict__ pre, const int* __restrict__ doc,
    __half* __restrict__ outh)
{
  const int b = blockIdx.x >> 1, dir = blockIdx.x & 1;
  const int tid = threadIdx.x, lane = tid & 63, wv = tid >> 6;
  const int L = doc[b];

  __shared__ __align__(16) signed char hq[2][256];   // i8 h, double-buffered

  if (tid < 128) ((unsigned*)hq)[tid] = 0u;          // h_{-1} = 0

  // W_hh i8 B-fragments: lane holds W[row=g*256+wv*32+nt*16+(lane&15)][kt*64+(lane>>4)*16 ..+16]
  i32x4 wfrag[2][4][4];
  #pragma unroll
  for (int nt = 0; nt < 2; ++nt)
    #pragma unroll
    for (int g = 0; g < 4; ++g){
      const int row = g*256 + wv*32 + nt*16 + (lane & 15);
      #pragma unroll
      for (int kt = 0; kt < 4; ++kt)
        wfrag[nt][g][kt] = *(const i32x4*)&W8[(size_t)dir*262144 + (size_t)row*256 + kt*64 + (lane>>4)*16];
    }

  const int u = wv*32 + (lane & 31);     // unit owned in gate phase (lanes 32-63 mirror 0-31)
  const int koff = (lane >> 4)*16;       // 16-byte k-chunk this lane supplies to the A-frag
  const int pos0 = dir ? (L-1) : 0;
  const __half* pp = pre + ((size_t)(b*S_ + pos0))*2048 + dir*1024 + u*4;
  __half*       op = outh + ((size_t)(b*S_ + pos0))*512 + dir*256 + u;
  const ptrdiff_t dp  = dir ? -2048 : 2048;   // halves per step (pre row)
  const ptrdiff_t dph = dir ? -512  : 512;    // halves per step (outh row)

  float cst = 0.f;
  uint2 pv, pvn = {0,0};
  pv = *(const uint2*)pp;                // lanes 32-63 load valid duplicates of lanes 0-31
  const i32x4 z = {0,0,0,0};
  BAR();

  for (int t = 0; t < L; ++t){
    // prefetch next step's pre operands (consumed after MFMA phase -> latency hidden)
    if (t+1 < L) pvn = *(const uint2*)(pp + dp);
    pp += dp;

    const int rbuf = (t+1) & 1, wbuf = t & 1;

    // broadcast A-fragments: uniform per 16-lane group -> LDS broadcast, conflict-free
    i32x4 af[4];
    #pragma unroll
    for (int kt = 0; kt < 4; ++kt)
      af[kt] = *(const i32x4*)&hq[rbuf][kt*64 + koff];

    // chained K-accumulate for one (nt, gate); all C rows identical -> a[0] is the gate sum
    auto chain4 = [&](const i32x4* w4) -> int {
      i32x4 a = __builtin_amdgcn_mfma_i32_16x16x64_i8(af[0], w4[0], z, 0, 0, 0);
      a = __builtin_amdgcn_mfma_i32_16x16x64_i8(af[1], w4[1], a, 0, 0, 0);
      a = __builtin_amdgcn_mfma_i32_16x16x64_i8(af[2], w4[2], a, 0, 0, 0);
      a = __builtin_amdgcn_mfma_i32_16x16x64_i8(af[3], w4[3], a, 0, 0, 0);
      return a[0];
    };

    const bool hi = (lane & 16) != 0;
    const __half2* ph = (const __half2*)&pv;
    const float2 p01 = __half22float2(ph[0]);
    const float2 p23 = __half22float2(ph[1]);

    // gates i,f,g first; c-chain VALU overlaps the o-gate MFMAs below
    const int i0 = chain4(wfrag[0][0]), i1 = chain4(wfrag[1][0]);
    const int f0 = chain4(wfrag[0][1]), f1 = chain4(wfrag[1][1]);
    const int q0 = chain4(wfrag[0][2]), q1 = chain4(wfrag[1][2]);
    const float giy = (float)(hi ? i1 : i0)*INVQ2 + p01.x;
    const float gfy = (float)(hi ? f1 : f0)*INVQ2 + p01.y;
    const float ggy = (float)(hi ? q1 : q0)*INVQ2 + p23.x;
    const int o0 = chain4(wfrag[0][3]), o1 = chain4(wfrag[1][3]);
    const float c = sigm2(gfy)*cst + sigm2(giy)*tanh2(ggy);
    cst = c;
    const float goy = (float)(hi ? o1 : o0)*INVQ2 + p23.y;
    const float hval = sigm2(goy)*tanh2(c*LOG2E);

    if (lane < 32){
      *op = __float2half(hval);
      hq[wbuf][u] = (signed char)(int)rintf(hval*127.0f);  // h in (-1,1): no clamp needed
    }
    op += dph;
    pv = pvn;
    BAR();
  }
}

// ---------- logits: wave per row (outh is f16) ----------
__global__ __launch_bounds__(256) void k_logits(const __half* __restrict__ outh, const float* __restrict__ mw,
    const float* __restrict__ mb, const int* __restrict__ doc, float* __restrict__ logits){
  const int w = threadIdx.x >> 6, lane = threadIdx.x & 63;
  const int r = blockIdx.x*4 + w;
  const int b = r >> 11, s = r & 2047;
  if (s >= doc[b]){
    if (lane < 13) logits[(size_t)r*13 + lane] = mb[lane];
    return;
  }
  float xv[8];
  #pragma unroll
  for (int m=0; m<8; ++m) xv[m] = __half2float(outh[(size_t)r*512 + lane + m*64]);
  #pragma unroll
  for (int k=0; k<13; ++k){
    float p = 0.f;
    #pragma unroll
    for (int m=0; m<8; ++m) p += xv[m]*mw[k*512 + lane + m*64];
    #pragma unroll
    for (int off=32; off; off>>=1) p += __shfl_down(p, off);
    if (lane == 0) logits[(size_t)r*13 + k] = p + mb[k];
  }
}

// ---------- CRF: one wave per batch; exp-transition matvec form ----------
__global__ void k_crf(const float* __restrict__ logits, const int* __restrict__ ntag,
    const int* __restrict__ doc, const float* __restrict__ trans,
    const float* __restrict__ stt, const float* __restrict__ ent, float* __restrict__ ll){
  const int b = blockIdx.x, lane = threadIdx.x;
  const int L = doc[b];
  const float* lg = logits + (size_t)b*S_*13;
  float et[13];
  #pragma unroll
  for (int i=0; i<13; ++i) et[i] = (lane < 13) ? __expf(trans[i*13 + lane]) : 0.f;
  float alpha = (lane < 13) ? (stt[lane] + lg[lane]) : -1e30f;
  float e_nxt = (L > 1 && lane < 13) ? lg[13 + lane] : 0.f;
  for (int t=1; t<L; ++t){
    const float e = e_nxt;
    if (t+1 < L && lane < 13) e_nxt = lg[(size_t)(t+1)*13 + lane];
    float m = alpha;
    #pragma unroll
    for (int off = 1; off < 16; off <<= 1) m = fmaxf(m, __shfl_xor(m, off));
    const float a = __expf(alpha - m);
    float s = 0.f;
    #pragma unroll
    for (int i=0; i<13; ++i) s += __shfl(a, i) * et[i];
    alpha = m + __logf(s) + e;
  }
  float av = (lane < 13) ? alpha + ent[lane] : -1e30f;
  float m2 = -1e30f;
  #pragma unroll
  for (int i=0; i<13; ++i) m2 = fmaxf(m2, __shfl(av, i));
  float s2 = 0.f;
  #pragma unroll
  for (int i=0; i<13; ++i) s2 += __expf(__shfl(av, i) - m2);
  const float logz = m2 + __logf(s2);
  const int* tg = ntag + (size_t)b*S_;
  float num = 0.f;
  for (int t = lane; t < L; t += 64){
    const int cur = tg[t];
    num += lg[(size_t)t*13 + cur];
    if (t >= 1) num += trans[tg[t-1]*13 + cur];
  }
  #pragma unroll
  for (int off=32; off; off>>=1) num += __shfl_down(num, off);
  if (lane == 0){
    num += stt[tg[0]] + ent[tg[L-1]];
    ll[b] = num - logz;
  }
}

extern "C" void kernel_launch(void* const* d_in, const int* in_sizes, int n_in,
                              void* d_out, int out_size, void* d_ws, size_t ws_size,
                              hipStream_t stream){
  const float* x    = (const float*)d_in[0];
  const float* gcn  = (const float*)d_in[1];
  const int* length = (const int*)d_in[3];
  const int* tags   = (const int*)d_in[4];
  const float* wihf = (const float*)d_in[5];
  const float* whhf = (const float*)d_in[6];
  const float* bf   = (const float*)d_in[7];
  const float* wihb = (const float*)d_in[8];
  const float* whhb = (const float*)d_in[9];
  const float* bb   = (const float*)d_in[10];
  const float* mw   = (const float*)d_in[11];
  const float* mb   = (const float*)d_in[12];
  const float* trans= (const float*)d_in[13];
  const float* stt  = (const float*)d_in[14];
  const float* ent  = (const float*)d_in[15];

  char* ws = (char*)d_ws;
  ushort* nx   = (ushort*)(ws + 0);              // 33,554,432 B  new_x bf16
  __half* pre  = (__half*)(ws + 33554432);       // 134,217,728 B pre-activations f16 (remapped, log2e-scaled)
  __half* outh = (__half*)(ws + 167772160);      // 33,554,432 B  concat h states (f16)
  ushort* wih  = (ushort*)(ws + 234881024);      // 2,097,152 B   w_ih bf16 [2048][512]
  signed char* whh8 = (signed char*)(ws + 236978176); // 524,288 B w_hh i8 [2][1024][256]
  int*    src  = (int*)(ws + 238026752);         // 131,072 B
  int*    ntag = (int*)(ws + 238157824);         // 131,072 B
  int*    cum  = (int*)(ws + 238288896);         // 4,096 B
  int*    doc  = (int*)(ws + 238292992);         // 64 B

  float* logits  = (float*)d_out;                // 425,984 floats
  float* maskout = logits + 425984;              // 32,768 floats
  float* ll      = maskout + 32768;              // 16 floats

  hipLaunchKernelGGL(k_prep,   dim3(1),        dim3(1024), 0, stream, length, cum, doc);
  hipLaunchKernelGGL(k_cast,   dim3(6144),     dim3(256),  0, stream, wihf, wihb, whhf, whhb, wih, whh8);
  hipLaunchKernelGGL(k_srcmap, dim3(128),      dim3(256),  0, stream, length, cum, tags, src, ntag);
  hipLaunchKernelGGL(k_newx,   dim3(32768),    dim3(256),  0, stream, x, gcn, src, doc, nx, maskout);
  hipLaunchKernelGGL(k_gemm,   dim3(256, 16),  dim3(256),  0, stream, nx, wih, bf, bb, doc, pre);
  hipLaunchKernelGGL(k_recur17, dim3(32),      dim3(512),  0, stream, whh8, pre, doc, outh);
  hipLaunchKernelGGL(k_logits, dim3(8192),     dim3(256),  0, stream, outh, mw, mb, doc, logits);
  hipLaunchKernelGGL(k_crf,    dim3(16),       dim3(64),   0, stream, logits, ntag, doc, trans, stt, ent, ll);
}